// Round 1
// baseline (529.615 us; speedup 1.0000x reference)
//
#include <hip/hip_runtime.h>
#include <hip/hip_bf16.h>

// ddstgcn: y = Conv1x2_dil2( concat([x, A0@x, A0@(A0@x), A1@x, A1@(A1@x), A2@x, A2@(A2@x)], ch) )
// Shapes: x[32,40,512,12] f32, A[32,512,512] f32 x3, W[20,280,2] f32, b[20] f32
// out y[32,20,512,10] f32.
//
// Strategy:
//  - diffusion einsum 'ncwl,nvw->ncvl' == per-(b) GEMM: D[v, col] = sum_w A[v,w] * X[col, w]
//    with col = c*12+l (480 cols), M=K=512. Done in bf16 MFMA (16x16x32), f32 accum.
//  - all staged tensors live in "TT" layout [.. ][col][v] (v contiguous) so GEMM B-operand
//    and conv reads are contiguous rows.
//  - workspace (bf16): xTT[32][480][512], x1TT[3*32][480][512], x2TT[3*32][480][512] = 110 MB.

typedef unsigned short u16;
typedef u16 u16x4 __attribute__((ext_vector_type(4)));
typedef u16 u16x8 __attribute__((ext_vector_type(8)));
typedef __bf16 bf16x8 __attribute__((ext_vector_type(8)));
typedef float f32x4 __attribute__((ext_vector_type(4)));

__device__ __forceinline__ u16 f2bf(float f) {
    unsigned int u = __float_as_uint(f);
    u += 0x7fffu + ((u >> 16) & 1u);   // round-to-nearest-even
    return (u16)(u >> 16);
}
__device__ __forceinline__ float bf2f(u16 h) {
    return __uint_as_float(((unsigned int)h) << 16);
}

// ---------------- prep: x[b,c,w,l] f32 -> xTT[b][(c*12+l)][w] bf16 ----------------
// thread i enumerates output elements (w fastest) -> coalesced 2B writes;
// reads are stride-12 f32 but fully L2/L3-absorbed (x is 31.5 MB).
__global__ __launch_bounds__(256) void prep_x(const float* __restrict__ x,
                                              u16* __restrict__ xTT) {
    int i = blockIdx.x * 256 + threadIdx.x;
    if (i >= 32 * 40 * 12 * 512) return;
    int w  = i & 511;
    int r  = i >> 9;          // r = (b*40+c)*12 + l
    int l  = r % 12;
    int cb = r / 12;          // b*40+c
    xTT[i] = f2bf(x[((size_t)cb * 512 + w) * 12 + l]);
}

// ---------------- diffusion GEMM ----------------
// D[v, col] = sum_w A_s[b][v][w] * X[col][w];  M=512 (v), N=480 (col), K=512 (w)
// block tile 128x96, BK=32, 4 waves (2x2), wave tile 64x48 (4x3 frags of 16x16).
// A converted f32->bf16 during staging. Output written bf16 in TT layout via LDS transpose.
__global__ __launch_bounds__(256) void gemm_diffuse(
    const float* __restrict__ A0, const float* __restrict__ A1, const float* __restrict__ A2,
    const u16* __restrict__ Xbase, size_t x_stride_s,
    u16* __restrict__ Obase)
{
    __shared__ u16 smem[13056];            // max(sA 5120 + sX 3840, epilogue 96*136)
    u16* sA = smem;                        // [128][40] (32 + 8 pad shorts per row)
    u16* sX = smem + 128 * 40;             // [96][40]

    const int t = threadIdx.x;
    const int z = blockIdx.z;              // s*32 + b
    const int s = z >> 5, b = z & 31;
    const float* Af = (s == 0 ? A0 : (s == 1 ? A1 : A2)) + (size_t)b * 512 * 512;
    const u16* Xb = Xbase + (size_t)b * 480 * 512 + (size_t)s * x_stride_s;
    u16* Ob = Obase + (size_t)z * 480 * 512;

    const int vblk = blockIdx.x * 128;     // gridDim.x = 4
    const int cblk = blockIdx.y * 96;      // gridDim.y = 5

    const int lane = t & 63, wid = t >> 6;
    const int wm = wid >> 1, wn = wid & 1;
    const int lrow = lane & 15, lk = (lane >> 4) * 8;

    f32x4 acc[4][3] = {};

    for (int kt = 0; kt < 16; ++kt) {
        const int w0 = kt * 32;
        // stage A tile 128x32 (f32 -> bf16): 1024 float4 chunks
        for (int id = t; id < 1024; id += 256) {
            int row = id >> 3, part = id & 7;
            float4 v = *(const float4*)(Af + (size_t)(vblk + row) * 512 + w0 + part * 4);
            u16x4 pk = { f2bf(v.x), f2bf(v.y), f2bf(v.z), f2bf(v.w) };
            *(u16x4*)(&sA[row * 40 + part * 4]) = pk;
        }
        // stage X tile 96x32 bf16: 384 16B chunks
        for (int id = t; id < 384; id += 256) {
            int row = id >> 2, part = id & 3;
            u16x8 v = *(const u16x8*)(Xb + (size_t)(cblk + row) * 512 + w0 + part * 8);
            *(u16x8*)(&sX[row * 40 + part * 8]) = v;
        }
        __syncthreads();

        bf16x8 af[4], xf[3];
        #pragma unroll
        for (int mf = 0; mf < 4; ++mf)
            af[mf] = *(const bf16x8*)(&sA[(wm * 64 + mf * 16 + lrow) * 40 + lk]);
        #pragma unroll
        for (int nf = 0; nf < 3; ++nf)
            xf[nf] = *(const bf16x8*)(&sX[(wn * 48 + nf * 16 + lrow) * 40 + lk]);
        #pragma unroll
        for (int mf = 0; mf < 4; ++mf)
            #pragma unroll
            for (int nf = 0; nf < 3; ++nf)
                acc[mf][nf] = __builtin_amdgcn_mfma_f32_16x16x32_bf16(
                    af[mf], xf[nf], acc[mf][nf], 0, 0, 0);
        __syncthreads();
    }

    // epilogue: acc -> LDS [col][v] (stride 136 shorts) -> coalesced bf16 TT store
    #pragma unroll
    for (int mf = 0; mf < 4; ++mf)
        #pragma unroll
        for (int nf = 0; nf < 3; ++nf) {
            int v   = wm * 64 + mf * 16 + (lane >> 4) * 4;   // C/D: row=(l>>4)*4+r
            int col = wn * 48 + nf * 16 + (lane & 15);       //      col=l&15
            f32x4 a = acc[mf][nf];
            u16x4 pk = { f2bf(a[0]), f2bf(a[1]), f2bf(a[2]), f2bf(a[3]) };
            *(u16x4*)(&smem[col * 136 + v]) = pk;
        }
    __syncthreads();
    for (int id = t; id < 1536; id += 256) {
        int col = id >> 4, chunk = id & 15;
        u16x8 val = *(const u16x8*)(&smem[col * 136 + chunk * 8]);
        *(u16x8*)(Ob + (size_t)(cblk + col) * 512 + vblk + chunk * 8) = val;
    }
}

// ---------------- conv epilogue ----------------
// y[b,o,v,l] = bias[o] + sum_{cc=0..279} W[o,cc,0]*h[b,cc,v,l] + W[o,cc,1]*h[b,cc,v,l+2]
// h channel cc -> segment seg=cc/40 (0:x, odd:x1[(seg-1)/2], even:x2[seg/2-1]), c=cc%40.
// block = (b, 64 v's); thread = (v_local, o-group of 5); W cached in LDS.
__global__ __launch_bounds__(256) void conv_out(
    const u16* __restrict__ xTT, const u16* __restrict__ x1TT, const u16* __restrict__ x2TT,
    const float* __restrict__ W, const float* __restrict__ bias, float* __restrict__ y)
{
    __shared__ float sW[20 * 280 * 2];
    __shared__ u16 sH[4 * 12 * 64];        // [cc_i][l][v]

    const int t = threadIdx.x;
    const int vt = blockIdx.x, b = blockIdx.y;
    const int v0 = vt * 64;
    const int vloc = t & 63, og = t >> 6;  // this thread: o in [og*5, og*5+5)

    for (int i = t; i < 11200; i += 256) sW[i] = W[i];

    float acc[5][10];
    #pragma unroll
    for (int j = 0; j < 5; ++j) {
        float bb = bias[og * 5 + j];
        #pragma unroll
        for (int l = 0; l < 10; ++l) acc[j][l] = bb;
    }
    __syncthreads();

    for (int cc0 = 0; cc0 < 280; cc0 += 4) {
        const int seg = cc0 / 40;          // chunk of 4 never crosses a segment (40%4==0)
        const u16* src;
        if (seg == 0)      src = xTT  + (size_t)b * 480 * 512;
        else if (seg & 1)  src = x1TT + (size_t)(((seg - 1) >> 1) * 32 + b) * 480 * 512;
        else               src = x2TT + (size_t)((seg / 2 - 1) * 32 + b) * 480 * 512;

        for (int id = t; id < 3072; id += 256) {
            int vv = id & 63;
            int rl = id >> 6;              // cc_i*12 + l
            int cc = cc0 + (rl / 12), l = rl % 12;
            int c = cc % 40;
            sH[id] = src[(size_t)(c * 12 + l) * 512 + v0 + vv];
        }
        __syncthreads();

        #pragma unroll
        for (int ci = 0; ci < 4; ++ci) {
            int cc = cc0 + ci;
            float h[12];
            #pragma unroll
            for (int l = 0; l < 12; ++l)
                h[l] = bf2f(sH[(ci * 12 + l) * 64 + vloc]);
            #pragma unroll
            for (int j = 0; j < 5; ++j) {
                int o = og * 5 + j;
                const float* wp = &sW[((size_t)o * 280 + cc) * 2];
                float w0 = wp[0], w1 = wp[1];
                #pragma unroll
                for (int l = 0; l < 10; ++l)
                    acc[j][l] += w0 * h[l] + w1 * h[l + 2];
            }
        }
        __syncthreads();
    }

    #pragma unroll
    for (int j = 0; j < 5; ++j) {
        int o = og * 5 + j;
        float* yp = y + (((size_t)b * 20 + o) * 512 + v0 + vloc) * 10;
        #pragma unroll
        for (int l = 0; l < 10; ++l) yp[l] = acc[j][l];
    }
}

extern "C" void kernel_launch(void* const* d_in, const int* in_sizes, int n_in,
                              void* d_out, int out_size, void* d_ws, size_t ws_size,
                              hipStream_t stream) {
    const float* x    = (const float*)d_in[0];
    const float* A0   = (const float*)d_in[1];
    const float* A1   = (const float*)d_in[2];
    const float* A2   = (const float*)d_in[3];
    const float* W    = (const float*)d_in[4];
    const float* bias = (const float*)d_in[5];
    float* y = (float*)d_out;

    // workspace layout (bf16 elements): xTT | x1TT | x2TT  = 110,100,480 bytes total
    u16* xTT  = (u16*)d_ws;
    u16* x1TT = xTT  + (size_t)32 * 480 * 512;          //  7,864,320 elems
    u16* x2TT = x1TT + (size_t)3 * 32 * 480 * 512;      // 23,592,960 elems

    prep_x<<<dim3((32 * 40 * 12 * 512 + 255) / 256), 256, 0, stream>>>(x, xTT);

    // pass 1: x1 = A_s @ x   (X shared across s)
    gemm_diffuse<<<dim3(4, 5, 96), 256, 0, stream>>>(A0, A1, A2, xTT, 0, x1TT);
    // pass 2: x2 = A_s @ x1  (X per (s,b))
    gemm_diffuse<<<dim3(4, 5, 96), 256, 0, stream>>>(A0, A1, A2, x1TT,
                                                     (size_t)32 * 480 * 512, x2TT);

    conv_out<<<dim3(8, 32), 256, 0, stream>>>(xTT, x1TT, x2TT, W, bias, y);
}

// Round 2
// 309.252 us; speedup vs baseline: 1.7126x; 1.7126x over previous
//
#include <hip/hip_runtime.h>
#include <hip/hip_bf16.h>

// ddstgcn via conv/diffusion commutation:
//   y = proj0(x) + bias + sum_s A_s @ ( p1_s(x) + A_s @ p2_s(x) )
// where proj_seg'(x)[o, v, l] = sum_{c,tap} W[o, seg'*40+c, tap] * x[c, v, l+2*tap]
// seg' in 0..6 maps [x, x1_0, x2_0, x1_1, x2_1, x1_2, x2_2] channel blocks.
// K1: all 7 projections as one MFMA GEMM (M=140 pad 144, K=80 pad 96, N=32*512*10)
// K2: t_s = p1_s + A_s @ p2_s   (per (s,b): M=512, N=200 pad 224, K=512)
// K3: y = proj0 + bias + sum_s A_s @ t_s  (M=512, N=224, K=3*512 fused)

typedef unsigned short u16;
typedef u16 u16x4 __attribute__((ext_vector_type(4)));
typedef u16 u16x8 __attribute__((ext_vector_type(8)));
typedef __bf16 bf16x8 __attribute__((ext_vector_type(8)));
typedef float f32x4 __attribute__((ext_vector_type(4)));

__device__ __forceinline__ u16 f2bf(float f) {
    unsigned int u = __float_as_uint(f);
    u += 0x7fffu + ((u >> 16) & 1u);   // RNE
    return (u16)(u >> 16);
}
__device__ __forceinline__ float bf2f(u16 h) {
    return __uint_as_float(((unsigned int)h) << 16);
}

// ---------------- K1: fused 7-way projection of x ----------------
// block = (vtile of 64, l, b); 4 waves; wave owns 16 v's x all 144 m's.
// A[m][k] = W[o*560 + sg*80 + k] (contiguous k!), m = sg*20+o, k = c*2+tap.
// B[v][k] = x[b, c, v0+v, l+2*tap].
__global__ __launch_bounds__(256) void proj_x(
    const float* __restrict__ x, const float* __restrict__ W,
    u16* __restrict__ P1, u16* __restrict__ P2, float* __restrict__ proj0)
{
    __shared__ u16 sA[144 * 104];
    __shared__ u16 sB[64 * 104];
    const int t = threadIdx.x;
    const int v0 = blockIdx.x * 64, l = blockIdx.y, b = blockIdx.z;

    // A tile from W (f32 -> bf16), zero-padded m>=140 / k>=80
    for (int id = t; id < 144 * 13; id += 256) {
        int m = id / 13, kc = id % 13, k0 = kc * 8;
        u16x8 val = {};
        if (m < 140 && k0 < 80) {
            int o = m % 20, sg = m / 20;
            const float* wp = W + o * 560 + sg * 80 + k0;
            float4 w0 = *(const float4*)wp;
            float4 w1 = *(const float4*)(wp + 4);
            val[0] = f2bf(w0.x); val[1] = f2bf(w0.y); val[2] = f2bf(w0.z); val[3] = f2bf(w0.w);
            val[4] = f2bf(w1.x); val[5] = f2bf(w1.y); val[6] = f2bf(w1.z); val[7] = f2bf(w1.w);
        }
        *(u16x8*)(&sA[m * 104 + k0]) = val;
    }
    // B tile (scalar gather from x; x is L2/L3-hot)
    for (int id = t; id < 5120; id += 256) {
        int v = id & 63, k = id >> 6;
        int c = k >> 1, tap = k & 1;
        float xv = x[((size_t)(b * 40 + c) * 512 + v0 + v) * 12 + l + 2 * tap];
        sB[v * 104 + k] = f2bf(xv);
    }
    for (int id = t; id < 64 * 3; id += 256) {     // zero pad k 80..103
        int v = id / 3, j = id % 3;
        u16x8 z = {};
        *(u16x8*)(&sB[v * 104 + 80 + j * 8]) = z;
    }
    __syncthreads();

    const int lane = t & 63, wid = t >> 6;
    const int lrow = lane & 15, lk = (lane >> 4) * 8;
    f32x4 acc[9] = {};
    #pragma unroll
    for (int ks = 0; ks < 3; ++ks) {
        bf16x8 xf = *(const bf16x8*)(&sB[(wid * 16 + lrow) * 104 + ks * 32 + lk]);
        #pragma unroll
        for (int mf = 0; mf < 9; ++mf) {
            bf16x8 af = *(const bf16x8*)(&sA[(mf * 16 + lrow) * 104 + ks * 32 + lk]);
            acc[mf] = __builtin_amdgcn_mfma_f32_16x16x32_bf16(af, xf, acc[mf], 0, 0, 0);
        }
    }

    // stores: D row = m, col = v (lane&15)
    const int v = v0 + wid * 16 + lrow;
    const int r4 = (lane >> 4) * 4;
    #pragma unroll
    for (int mf = 0; mf < 9; ++mf)
        #pragma unroll
        for (int i = 0; i < 4; ++i) {
            int m = mf * 16 + r4 + i;
            if (m < 140) {
                int o = m % 20, sg = m / 20;
                float val = acc[mf][i];
                if (sg == 0) {
                    proj0[((size_t)(b * 20 + o) * 10 + l) * 512 + v] = val;
                } else {
                    int s = (sg - 1) >> 1;
                    u16* dst = ((sg - 1) & 1) ? P2 : P1;
                    dst[((size_t)(s * 32 + b) * 200 + o * 10 + l) * 512 + v] = f2bf(val);
                }
            }
        }
}

// ---------------- K2: t_s = p1_s + A_s @ p2_s ----------------
// grid (vt 4, ct 2, z=s*32+b 96). block tile M128 x N112, BK=32, 4 waves (4Mx1N).
// reg-prefetch pipeline; epilogue: bf16 LDS transpose + p1 add -> T[z][col][v] bf16.
__global__ __launch_bounds__(256) void gemm_t(
    const float* __restrict__ A0, const float* __restrict__ A1, const float* __restrict__ A2,
    const u16* __restrict__ P1, const u16* __restrict__ P2, u16* __restrict__ T)
{
    __shared__ u16 smem[112 * 136];        // epilogue [112][136]; main loop: sA(5120)+sX(4480)
    u16* sA = smem;                        // [128][40]
    u16* sX = smem + 5120;                 // [112][40]

    const int t = threadIdx.x;
    const int vblk = blockIdx.x * 128, cblk = blockIdx.y * 112;
    const int z = blockIdx.z, s = z >> 5, b = z & 31;
    const float* Af = (s == 0 ? A0 : (s == 1 ? A1 : A2)) + (size_t)b * 512 * 512;
    const u16* Xb = P2 + (size_t)z * 200 * 512;

    const int lane = t & 63, wid = t >> 6;
    const int lrow = lane & 15, lk = (lane >> 4) * 8;

    float4 ar[4];
    u16x8 xr[2];
    auto load_regs = [&](int kt) {
        const int w0 = kt * 32;
        #pragma unroll
        for (int i = 0; i < 4; ++i) {
            int id = t + i * 256, row = id >> 3, part = id & 7;
            ar[i] = *(const float4*)(Af + (size_t)(vblk + row) * 512 + w0 + part * 4);
        }
        #pragma unroll
        for (int i = 0; i < 2; ++i) {
            int id = t + i * 256;
            if (id < 448) {
                int row = id >> 2, part = id & 3, rg = cblk + row;
                u16x8 zv = {};
                xr[i] = (rg < 200) ? *(const u16x8*)(Xb + (size_t)rg * 512 + w0 + part * 8) : zv;
            }
        }
    };
    auto store_lds = [&]() {
        #pragma unroll
        for (int i = 0; i < 4; ++i) {
            int id = t + i * 256, row = id >> 3, part = id & 7;
            u16x4 pk = { f2bf(ar[i].x), f2bf(ar[i].y), f2bf(ar[i].z), f2bf(ar[i].w) };
            *(u16x4*)(&sA[row * 40 + part * 4]) = pk;
        }
        #pragma unroll
        for (int i = 0; i < 2; ++i) {
            int id = t + i * 256;
            if (id < 448) {
                int row = id >> 2, part = id & 3;
                *(u16x8*)(&sX[row * 40 + part * 8]) = xr[i];
            }
        }
    };

    f32x4 acc[2][7] = {};
    load_regs(0);
    for (int kt = 0; kt < 16; ++kt) {
        store_lds();
        __syncthreads();
        if (kt < 15) load_regs(kt + 1);
        bf16x8 af[2], xf[7];
        #pragma unroll
        for (int mf = 0; mf < 2; ++mf)
            af[mf] = *(const bf16x8*)(&sA[(wid * 32 + mf * 16 + lrow) * 40 + lk]);
        #pragma unroll
        for (int nf = 0; nf < 7; ++nf)
            xf[nf] = *(const bf16x8*)(&sX[(nf * 16 + lrow) * 40 + lk]);
        #pragma unroll
        for (int mf = 0; mf < 2; ++mf)
            #pragma unroll
            for (int nf = 0; nf < 7; ++nf)
                acc[mf][nf] = __builtin_amdgcn_mfma_f32_16x16x32_bf16(
                    af[mf], xf[nf], acc[mf][nf], 0, 0, 0);
        __syncthreads();
    }

    // epilogue: transpose to [col][v] bf16, add p1, store T
    #pragma unroll
    for (int mf = 0; mf < 2; ++mf)
        #pragma unroll
        for (int nf = 0; nf < 7; ++nf) {
            int v = wid * 32 + mf * 16 + (lane >> 4) * 4;
            int col = nf * 16 + lrow;
            f32x4 a = acc[mf][nf];
            u16x4 pk = { f2bf(a[0]), f2bf(a[1]), f2bf(a[2]), f2bf(a[3]) };
            *(u16x4*)(&smem[col * 136 + v]) = pk;
        }
    __syncthreads();
    u16* Tb = T + (size_t)z * 200 * 512;
    const u16* P1b = P1 + (size_t)z * 200 * 512;
    for (int id = t; id < 112 * 16; id += 256) {
        int row = id >> 4, c8 = (id & 15) * 8, rg = cblk + row;
        if (rg < 200) {
            u16x8 rv = *(const u16x8*)(&smem[row * 136 + c8]);
            u16x8 pv = *(const u16x8*)(P1b + (size_t)rg * 512 + vblk + c8);
            u16x8 out;
            #pragma unroll
            for (int j = 0; j < 8; ++j) out[j] = f2bf(bf2f(rv[j]) + bf2f(pv[j]));
            *(u16x8*)(Tb + (size_t)rg * 512 + vblk + c8) = out;
        }
    }
}

// ---------------- K3: y = proj0 + bias + sum_s A_s @ t_s ----------------
// grid (vt 4, ct 2, b 32). K = 3*512 fused (phase s = kt>>4). Epilogue: f32 LDS
// transpose, add proj0 + bias, strided f32 stores to y[b,o,v,l].
__global__ __launch_bounds__(256) void gemm_y(
    const float* __restrict__ A0, const float* __restrict__ A1, const float* __restrict__ A2,
    const u16* __restrict__ T, const float* __restrict__ proj0,
    const float* __restrict__ bias, float* __restrict__ y)
{
    __shared__ float sE[112 * 132];        // 59.1 KB epilogue; main loop overlays as u16
    u16* sA = (u16*)sE;                    // [128][40]
    u16* sX = (u16*)sE + 5120;             // [112][40]

    const int t = threadIdx.x;
    const int vblk = blockIdx.x * 128, cblk = blockIdx.y * 112;
    const int b = blockIdx.z;
    const float* Ap0 = A0 + (size_t)b * 512 * 512;
    const float* Ap1 = A1 + (size_t)b * 512 * 512;
    const float* Ap2 = A2 + (size_t)b * 512 * 512;
    const u16* Xp0 = T + (size_t)(0 * 32 + b) * 200 * 512;
    const u16* Xp1 = T + (size_t)(1 * 32 + b) * 200 * 512;
    const u16* Xp2 = T + (size_t)(2 * 32 + b) * 200 * 512;

    const int lane = t & 63, wid = t >> 6;
    const int lrow = lane & 15, lk = (lane >> 4) * 8;

    float4 ar[4];
    u16x8 xr[2];
    auto load_regs = [&](int kt) {
        const int s = kt >> 4, w0 = (kt & 15) * 32;
        const float* Af = (s == 0 ? Ap0 : (s == 1 ? Ap1 : Ap2));
        const u16* Xb = (s == 0 ? Xp0 : (s == 1 ? Xp1 : Xp2));
        #pragma unroll
        for (int i = 0; i < 4; ++i) {
            int id = t + i * 256, row = id >> 3, part = id & 7;
            ar[i] = *(const float4*)(Af + (size_t)(vblk + row) * 512 + w0 + part * 4);
        }
        #pragma unroll
        for (int i = 0; i < 2; ++i) {
            int id = t + i * 256;
            if (id < 448) {
                int row = id >> 2, part = id & 3, rg = cblk + row;
                u16x8 zv = {};
                xr[i] = (rg < 200) ? *(const u16x8*)(Xb + (size_t)rg * 512 + w0 + part * 8) : zv;
            }
        }
    };
    auto store_lds = [&]() {
        #pragma unroll
        for (int i = 0; i < 4; ++i) {
            int id = t + i * 256, row = id >> 3, part = id & 7;
            u16x4 pk = { f2bf(ar[i].x), f2bf(ar[i].y), f2bf(ar[i].z), f2bf(ar[i].w) };
            *(u16x4*)(&sA[row * 40 + part * 4]) = pk;
        }
        #pragma unroll
        for (int i = 0; i < 2; ++i) {
            int id = t + i * 256;
            if (id < 448) {
                int row = id >> 2, part = id & 3;
                *(u16x8*)(&sX[row * 40 + part * 8]) = xr[i];
            }
        }
    };

    f32x4 acc[2][7] = {};
    load_regs(0);
    for (int kt = 0; kt < 48; ++kt) {
        store_lds();
        __syncthreads();
        if (kt < 47) load_regs(kt + 1);
        bf16x8 af[2], xf[7];
        #pragma unroll
        for (int mf = 0; mf < 2; ++mf)
            af[mf] = *(const bf16x8*)(&sA[(wid * 32 + mf * 16 + lrow) * 40 + lk]);
        #pragma unroll
        for (int nf = 0; nf < 7; ++nf)
            xf[nf] = *(const bf16x8*)(&sX[(nf * 16 + lrow) * 40 + lk]);
        #pragma unroll
        for (int mf = 0; mf < 2; ++mf)
            #pragma unroll
            for (int nf = 0; nf < 7; ++nf)
                acc[mf][nf] = __builtin_amdgcn_mfma_f32_16x16x32_bf16(
                    af[mf], xf[nf], acc[mf][nf], 0, 0, 0);
        __syncthreads();
    }

    // epilogue: f32 transpose -> [col][v], add proj0 + bias, store y
    #pragma unroll
    for (int mf = 0; mf < 2; ++mf)
        #pragma unroll
        for (int nf = 0; nf < 7; ++nf) {
            int v = wid * 32 + mf * 16 + (lane >> 4) * 4;
            int col = nf * 16 + lrow;
            *(f32x4*)(&sE[col * 132 + v]) = acc[mf][nf];
        }
    __syncthreads();
    for (int id = t; id < 112 * 32; id += 256) {
        int col = id >> 5, v4 = (id & 31) * 4, cg = cblk + col;
        if (cg < 200) {
            int o = cg / 10, l = cg % 10;
            f32x4 av = *(const f32x4*)(&sE[col * 132 + v4]);
            float4 pv = *(const float4*)(proj0 + ((size_t)(b * 20 + o) * 10 + l) * 512 + vblk + v4);
            float bb = bias[o];
            float* yp = y + ((size_t)(b * 20 + o) * 512 + vblk + v4) * 10 + l;
            yp[0]  = av[0] + pv.x + bb;
            yp[10] = av[1] + pv.y + bb;
            yp[20] = av[2] + pv.z + bb;
            yp[30] = av[3] + pv.w + bb;
        }
    }
}

extern "C" void kernel_launch(void* const* d_in, const int* in_sizes, int n_in,
                              void* d_out, int out_size, void* d_ws, size_t ws_size,
                              hipStream_t stream) {
    const float* x    = (const float*)d_in[0];
    const float* A0   = (const float*)d_in[1];
    const float* A1   = (const float*)d_in[2];
    const float* A2   = (const float*)d_in[3];
    const float* W    = (const float*)d_in[4];
    const float* bias = (const float*)d_in[5];
    float* y = (float*)d_out;

    // ws: P1[3*32][200][512] bf16 | P2 same | T same | proj0[32][20][10][512] f32 = 72.1 MB
    const size_t PSZ = (size_t)3 * 32 * 200 * 512;
    u16* P1 = (u16*)d_ws;
    u16* P2 = P1 + PSZ;
    u16* T  = P2 + PSZ;
    float* proj0 = (float*)(T + PSZ);

    proj_x<<<dim3(8, 10, 32), 256, 0, stream>>>(x, W, P1, P2, proj0);
    gemm_t<<<dim3(4, 2, 96), 256, 0, stream>>>(A0, A1, A2, P1, P2, T);
    gemm_y<<<dim3(4, 2, 32), 256, 0, stream>>>(A0, A1, A2, T, proj0, bias, y);
}

// Round 3
// 152.599 us; speedup vs baseline: 3.4706x; 2.0266x over previous
//
#include <hip/hip_runtime.h>
#include <hip/hip_bf16.h>

// ddstgcn via conv/diffusion commutation:
//   y = proj0(x) + bias + sum_s A_s @ ( p1_s(x) + A_s @ p2_s(x) )
// K1 proj_x : 7 channel projections of x (one MFMA GEMM) -> P1, P2 (bf16), proj0 (f32)
// K2 gemm_t : T := P1 + A_s @ P2, in-place over P1.  per (s,b): M=512(v) N=200 K=512
// K3 gemm_yp: Ypart[s] = A_s @ T_s  (f32 partials, direct coalesced stores)
// K4 reduce : y = proj0 + bias + sum_s Ypart[s]
//
// MFMA operand order is mfma(xf, af): D-"row" dim = X rows (= output col o*10+l),
// D-"col" dim = A rows (= node v, lane&15) -> epilogue stores are v-contiguous.

typedef unsigned short u16;
typedef u16 u16x4 __attribute__((ext_vector_type(4)));
typedef u16 u16x8 __attribute__((ext_vector_type(8)));
typedef __bf16 bf16x8 __attribute__((ext_vector_type(8)));
typedef float f32x4 __attribute__((ext_vector_type(4)));

__device__ __forceinline__ u16 f2bf(float f) {
    unsigned int u = __float_as_uint(f);
    u += 0x7fffu + ((u >> 16) & 1u);   // RNE
    return (u16)(u >> 16);
}
__device__ __forceinline__ float bf2f(u16 h) {
    return __uint_as_float(((unsigned int)h) << 16);
}

// ---------------- K1: fused 7-way projection of x ----------------
// block = (vtile of 64, l, b); 4 waves; wave owns 16 v's x all 144 m's.
// A[m][k] = W[o*560 + sg*80 + k], m = sg*20+o, k = c*2+tap. B[v][k] = x[b,c,v0+v,l+2tap].
__global__ __launch_bounds__(256) void proj_x(
    const float* __restrict__ x, const float* __restrict__ W,
    u16* __restrict__ P1, u16* __restrict__ P2, float* __restrict__ proj0)
{
    __shared__ u16 sA[144 * 104];
    __shared__ u16 sB[64 * 104];
    const int t = threadIdx.x;
    const int v0 = blockIdx.x * 64, l = blockIdx.y, b = blockIdx.z;

    for (int id = t; id < 144 * 13; id += 256) {
        int m = id / 13, kc = id % 13, k0 = kc * 8;
        u16x8 val = {};
        if (m < 140 && k0 < 80) {
            int o = m % 20, sg = m / 20;
            const float* wp = W + o * 560 + sg * 80 + k0;
            float4 w0 = *(const float4*)wp;
            float4 w1 = *(const float4*)(wp + 4);
            val[0] = f2bf(w0.x); val[1] = f2bf(w0.y); val[2] = f2bf(w0.z); val[3] = f2bf(w0.w);
            val[4] = f2bf(w1.x); val[5] = f2bf(w1.y); val[6] = f2bf(w1.z); val[7] = f2bf(w1.w);
        }
        *(u16x8*)(&sA[m * 104 + k0]) = val;
    }
    for (int id = t; id < 5120; id += 256) {
        int v = id & 63, k = id >> 6;
        int c = k >> 1, tap = k & 1;
        float xv = x[((size_t)(b * 40 + c) * 512 + v0 + v) * 12 + l + 2 * tap];
        sB[v * 104 + k] = f2bf(xv);
    }
    for (int id = t; id < 64 * 3; id += 256) {
        int v = id / 3, j = id % 3;
        u16x8 z = {};
        *(u16x8*)(&sB[v * 104 + 80 + j * 8]) = z;
    }
    __syncthreads();

    const int lane = t & 63, wid = t >> 6;
    const int lrow = lane & 15, lk = (lane >> 4) * 8;
    f32x4 acc[9] = {};
    #pragma unroll
    for (int ks = 0; ks < 3; ++ks) {
        bf16x8 xf = *(const bf16x8*)(&sB[(wid * 16 + lrow) * 104 + ks * 32 + lk]);
        #pragma unroll
        for (int mf = 0; mf < 9; ++mf) {
            bf16x8 af = *(const bf16x8*)(&sA[(mf * 16 + lrow) * 104 + ks * 32 + lk]);
            acc[mf] = __builtin_amdgcn_mfma_f32_16x16x32_bf16(af, xf, acc[mf], 0, 0, 0);
        }
    }

    const int v = v0 + wid * 16 + lrow;
    const int r4 = (lane >> 4) * 4;
    #pragma unroll
    for (int mf = 0; mf < 9; ++mf)
        #pragma unroll
        for (int i = 0; i < 4; ++i) {
            int m = mf * 16 + r4 + i;
            if (m < 140) {
                int o = m % 20, sg = m / 20;
                float val = acc[mf][i];
                if (sg == 0) {
                    proj0[((size_t)(b * 20 + o) * 10 + l) * 512 + v] = val;
                } else {
                    int s = (sg - 1) >> 1;
                    u16* dst = ((sg - 1) & 1) ? P2 : P1;
                    dst[((size_t)(s * 32 + b) * 200 + o * 10 + l) * 512 + v] = f2bf(val);
                }
            }
        }
}

// ---------------- K2: T := P1 + A_s @ P2 (in-place over P1) ----------------
// grid (vt 8, z 96); 256 thr / 4 waves; block tile v64 x col224(200); BK=32.
__global__ __launch_bounds__(256) void gemm_t(
    const float* __restrict__ A0, const float* __restrict__ A1, const float* __restrict__ A2,
    const u16* __restrict__ P2, u16* __restrict__ T)
{
    __shared__ u16 sA[64 * 40];            // A bf16 tile [64 v][32+8pad]
    __shared__ u16 sX[224 * 40];           // X tile [224 col][32+8pad]
    const int t = threadIdx.x;
    const int vblk = blockIdx.x * 64;
    const int z = blockIdx.y, s = z >> 5, b = z & 31;
    const float* Af = (s == 0 ? A0 : (s == 1 ? A1 : A2)) + (size_t)b * 512 * 512;
    const u16* Xb = P2 + (size_t)z * 200 * 512;
    const int lane = t & 63, wid = t >> 6;
    const int wcol = wid >> 1, wv = wid & 1;
    const int lrow = lane & 15, lk = (lane >> 4) * 8;

    float4 ar[2];
    u16x8 xr[4];
    auto load_regs = [&](int kt) {
        const int w0 = kt * 32;
        #pragma unroll
        for (int i = 0; i < 2; ++i) {
            int id = t + i * 256, row = id >> 3, part = id & 7;
            ar[i] = *(const float4*)(Af + (size_t)(vblk + row) * 512 + w0 + part * 4);
        }
        #pragma unroll
        for (int i = 0; i < 4; ++i) {
            int id = t + i * 256;
            if (id < 896) {
                int row = id >> 2, part = id & 3;
                u16x8 zv = {};
                xr[i] = (row < 200) ? *(const u16x8*)(Xb + (size_t)row * 512 + w0 + part * 8) : zv;
            }
        }
    };
    auto store_lds = [&]() {
        #pragma unroll
        for (int i = 0; i < 2; ++i) {
            int id = t + i * 256, row = id >> 3, part = id & 7;
            u16x4 pk = { f2bf(ar[i].x), f2bf(ar[i].y), f2bf(ar[i].z), f2bf(ar[i].w) };
            *(u16x4*)(&sA[row * 40 + part * 4]) = pk;
        }
        #pragma unroll
        for (int i = 0; i < 4; ++i) {
            int id = t + i * 256;
            if (id < 896) {
                int row = id >> 2, part = id & 3;
                *(u16x8*)(&sX[row * 40 + part * 8]) = xr[i];
            }
        }
    };

    f32x4 acc[7][2] = {};
    load_regs(0);
    for (int kt = 0; kt < 16; ++kt) {
        store_lds();
        __syncthreads();
        if (kt < 15) load_regs(kt + 1);
        bf16x8 af[2];
        #pragma unroll
        for (int vf = 0; vf < 2; ++vf)
            af[vf] = *(const bf16x8*)(&sA[(wv * 32 + vf * 16 + lrow) * 40 + lk]);
        #pragma unroll
        for (int cf = 0; cf < 7; ++cf) {
            bf16x8 xf = *(const bf16x8*)(&sX[(wcol * 112 + cf * 16 + lrow) * 40 + lk]);
            #pragma unroll
            for (int vf = 0; vf < 2; ++vf)
                acc[cf][vf] = __builtin_amdgcn_mfma_f32_16x16x32_bf16(
                    xf, af[vf], acc[cf][vf], 0, 0, 0);
        }
        __syncthreads();
    }

    u16* Tz = T + (size_t)z * 200 * 512;
    #pragma unroll
    for (int cf = 0; cf < 7; ++cf)
        #pragma unroll
        for (int vf = 0; vf < 2; ++vf)
            #pragma unroll
            for (int i = 0; i < 4; ++i) {
                int col = wcol * 112 + cf * 16 + (lane >> 4) * 4 + i;
                if (col < 200) {
                    int v = vblk + wv * 32 + vf * 16 + (lane & 15);
                    size_t idx = (size_t)col * 512 + v;
                    Tz[idx] = f2bf(acc[cf][vf][i] + bf2f(Tz[idx]));
                }
            }
}

// ---------------- K3: Ypart[z] = A_s @ T_s (f32, direct stores) ----------------
__global__ __launch_bounds__(256) void gemm_yp(
    const float* __restrict__ A0, const float* __restrict__ A1, const float* __restrict__ A2,
    const u16* __restrict__ T, float* __restrict__ Ypart)
{
    __shared__ u16 sA[64 * 40];
    __shared__ u16 sX[224 * 40];
    const int t = threadIdx.x;
    const int vblk = blockIdx.x * 64;
    const int z = blockIdx.y, s = z >> 5, b = z & 31;
    const float* Af = (s == 0 ? A0 : (s == 1 ? A1 : A2)) + (size_t)b * 512 * 512;
    const u16* Xb = T + (size_t)z * 200 * 512;
    const int lane = t & 63, wid = t >> 6;
    const int wcol = wid >> 1, wv = wid & 1;
    const int lrow = lane & 15, lk = (lane >> 4) * 8;

    float4 ar[2];
    u16x8 xr[4];
    auto load_regs = [&](int kt) {
        const int w0 = kt * 32;
        #pragma unroll
        for (int i = 0; i < 2; ++i) {
            int id = t + i * 256, row = id >> 3, part = id & 7;
            ar[i] = *(const float4*)(Af + (size_t)(vblk + row) * 512 + w0 + part * 4);
        }
        #pragma unroll
        for (int i = 0; i < 4; ++i) {
            int id = t + i * 256;
            if (id < 896) {
                int row = id >> 2, part = id & 3;
                u16x8 zv = {};
                xr[i] = (row < 200) ? *(const u16x8*)(Xb + (size_t)row * 512 + w0 + part * 8) : zv;
            }
        }
    };
    auto store_lds = [&]() {
        #pragma unroll
        for (int i = 0; i < 2; ++i) {
            int id = t + i * 256, row = id >> 3, part = id & 7;
            u16x4 pk = { f2bf(ar[i].x), f2bf(ar[i].y), f2bf(ar[i].z), f2bf(ar[i].w) };
            *(u16x4*)(&sA[row * 40 + part * 4]) = pk;
        }
        #pragma unroll
        for (int i = 0; i < 4; ++i) {
            int id = t + i * 256;
            if (id < 896) {
                int row = id >> 2, part = id & 3;
                *(u16x8*)(&sX[row * 40 + part * 8]) = xr[i];
            }
        }
    };

    f32x4 acc[7][2] = {};
    load_regs(0);
    for (int kt = 0; kt < 16; ++kt) {
        store_lds();
        __syncthreads();
        if (kt < 15) load_regs(kt + 1);
        bf16x8 af[2];
        #pragma unroll
        for (int vf = 0; vf < 2; ++vf)
            af[vf] = *(const bf16x8*)(&sA[(wv * 32 + vf * 16 + lrow) * 40 + lk]);
        #pragma unroll
        for (int cf = 0; cf < 7; ++cf) {
            bf16x8 xf = *(const bf16x8*)(&sX[(wcol * 112 + cf * 16 + lrow) * 40 + lk]);
            #pragma unroll
            for (int vf = 0; vf < 2; ++vf)
                acc[cf][vf] = __builtin_amdgcn_mfma_f32_16x16x32_bf16(
                    xf, af[vf], acc[cf][vf], 0, 0, 0);
        }
        __syncthreads();
    }

    float* Yz = Ypart + (size_t)z * 200 * 512;
    #pragma unroll
    for (int cf = 0; cf < 7; ++cf)
        #pragma unroll
        for (int vf = 0; vf < 2; ++vf)
            #pragma unroll
            for (int i = 0; i < 4; ++i) {
                int col = wcol * 112 + cf * 16 + (lane >> 4) * 4 + i;
                if (col < 200) {
                    int v = vblk + wv * 32 + vf * 16 + (lane & 15);
                    Yz[(size_t)col * 512 + v] = acc[cf][vf][i];
                }
            }
}

// ---------------- K4: y = proj0 + bias + sum_s Ypart[s] ----------------
__global__ __launch_bounds__(256) void reduce_y(
    const float* __restrict__ Ypart, const float* __restrict__ proj0,
    const float* __restrict__ bias, float* __restrict__ y)
{
    int i = blockIdx.x * 256 + threadIdx.x;   // over 32*20*512
    if (i >= 32 * 20 * 512) return;
    int v = i & 511;
    int r = i >> 9;
    int o = r % 20, b = r / 20;
    float bb = bias[o];
    float* yp = y + ((size_t)r * 512 + v) * 10;
    #pragma unroll
    for (int l = 0; l < 10; ++l) {
        float sum = proj0[((size_t)r * 10 + l) * 512 + v] + bb;
        #pragma unroll
        for (int s = 0; s < 3; ++s)
            sum += Ypart[((size_t)(s * 32 + b) * 200 + o * 10 + l) * 512 + v];
        yp[l] = sum;
    }
}

extern "C" void kernel_launch(void* const* d_in, const int* in_sizes, int n_in,
                              void* d_out, int out_size, void* d_ws, size_t ws_size,
                              hipStream_t stream) {
    const float* x    = (const float*)d_in[0];
    const float* A0   = (const float*)d_in[1];
    const float* A1   = (const float*)d_in[2];
    const float* A2   = (const float*)d_in[3];
    const float* W    = (const float*)d_in[4];
    const float* bias = (const float*)d_in[5];
    float* y = (float*)d_out;

    // ws: P1/T [96][200][512] bf16 | P2 same | proj0 [32][20][10][512] f32 | Ypart [96][200][512] f32
    const size_t PSZ = (size_t)96 * 200 * 512;        // 9,830,400 elems
    u16* P1 = (u16*)d_ws;                             // 19.66 MB (becomes T in-place)
    u16* P2 = P1 + PSZ;                               // 19.66 MB
    float* proj0 = (float*)(P2 + PSZ);                // 13.11 MB
    float* Ypart = proj0 + (size_t)32 * 20 * 10 * 512;// 39.32 MB   (total 91.8 MB)

    proj_x<<<dim3(8, 10, 32), 256, 0, stream>>>(x, W, P1, P2, proj0);
    gemm_t<<<dim3(8, 96), 256, 0, stream>>>(A0, A1, A2, P2, P1);      // T := P1 + A@P2
    gemm_yp<<<dim3(8, 96), 256, 0, stream>>>(A0, A1, A2, P1, Ypart);  // Ypart = A@T
    reduce_y<<<dim3(1280), 256, 0, stream>>>(Ypart, proj0, bias, y);
}

// Round 4
// 120.965 us; speedup vs baseline: 4.3783x; 1.2615x over previous
//
#include <hip/hip_runtime.h>
#include <hip/hip_bf16.h>

// ddstgcn via conv/diffusion commutation:
//   y = proj0(x) + bias + sum_s A_s @ ( p1_s(x) + A_s @ p2_s(x) )
// K1 proj_x : 7 channel projections of x (one MFMA GEMM) -> P1, P2 (bf16), proj0 (f32)
// K2 gemm_t : T := P1 + A_s @ P2, in-place over P1.  per (s,b): M=512(v) N=200 K=512
// K3 gemm_yp: Ypart[s] = A_s @ T_s  (f32 partials, direct coalesced stores)
// K4 reduce : y = proj0 + bias + sum_s Ypart[s]
//
// Round-3 changes: col-split GEMM tiles (v64 x col112) -> 1536 blocks (6/CU, was 3/CU);
// XCD-aware block swizzle so all blocks of one z share an XCD L2; 16B sA staging stores.

typedef unsigned short u16;
typedef u16 u16x4 __attribute__((ext_vector_type(4)));
typedef u16 u16x8 __attribute__((ext_vector_type(8)));
typedef __bf16 bf16x8 __attribute__((ext_vector_type(8)));
typedef float f32x4 __attribute__((ext_vector_type(4)));

__device__ __forceinline__ u16 f2bf(float f) {
    unsigned int u = __float_as_uint(f);
    u += 0x7fffu + ((u >> 16) & 1u);   // RNE
    return (u16)(u >> 16);
}
__device__ __forceinline__ float bf2f(u16 h) {
    return __uint_as_float(((unsigned int)h) << 16);
}

// ---------------- K1: fused 7-way projection of x ----------------
__global__ __launch_bounds__(256) void proj_x(
    const float* __restrict__ x, const float* __restrict__ W,
    u16* __restrict__ P1, u16* __restrict__ P2, float* __restrict__ proj0)
{
    __shared__ u16 sA[144 * 104];
    __shared__ u16 sB[64 * 104];
    const int t = threadIdx.x;
    const int v0 = blockIdx.x * 64, l = blockIdx.y, b = blockIdx.z;

    for (int id = t; id < 144 * 13; id += 256) {
        int m = id / 13, kc = id % 13, k0 = kc * 8;
        u16x8 val = {};
        if (m < 140 && k0 < 80) {
            int o = m % 20, sg = m / 20;
            const float* wp = W + o * 560 + sg * 80 + k0;
            float4 w0 = *(const float4*)wp;
            float4 w1 = *(const float4*)(wp + 4);
            val[0] = f2bf(w0.x); val[1] = f2bf(w0.y); val[2] = f2bf(w0.z); val[3] = f2bf(w0.w);
            val[4] = f2bf(w1.x); val[5] = f2bf(w1.y); val[6] = f2bf(w1.z); val[7] = f2bf(w1.w);
        }
        *(u16x8*)(&sA[m * 104 + k0]) = val;
    }
    for (int id = t; id < 5120; id += 256) {
        int v = id & 63, k = id >> 6;
        int c = k >> 1, tap = k & 1;
        float xv = x[((size_t)(b * 40 + c) * 512 + v0 + v) * 12 + l + 2 * tap];
        sB[v * 104 + k] = f2bf(xv);
    }
    for (int id = t; id < 64 * 3; id += 256) {
        int v = id / 3, j = id % 3;
        u16x8 z = {};
        *(u16x8*)(&sB[v * 104 + 80 + j * 8]) = z;
    }
    __syncthreads();

    const int lane = t & 63, wid = t >> 6;
    const int lrow = lane & 15, lk = (lane >> 4) * 8;
    f32x4 acc[9] = {};
    #pragma unroll
    for (int ks = 0; ks < 3; ++ks) {
        bf16x8 xf = *(const bf16x8*)(&sB[(wid * 16 + lrow) * 104 + ks * 32 + lk]);
        #pragma unroll
        for (int mf = 0; mf < 9; ++mf) {
            bf16x8 af = *(const bf16x8*)(&sA[(mf * 16 + lrow) * 104 + ks * 32 + lk]);
            acc[mf] = __builtin_amdgcn_mfma_f32_16x16x32_bf16(af, xf, acc[mf], 0, 0, 0);
        }
    }

    const int v = v0 + wid * 16 + lrow;
    const int r4 = (lane >> 4) * 4;
    #pragma unroll
    for (int mf = 0; mf < 9; ++mf)
        #pragma unroll
        for (int i = 0; i < 4; ++i) {
            int m = mf * 16 + r4 + i;
            if (m < 140) {
                int o = m % 20, sg = m / 20;
                float val = acc[mf][i];
                if (sg == 0) {
                    proj0[((size_t)(b * 20 + o) * 10 + l) * 512 + v] = val;
                } else {
                    int s = (sg - 1) >> 1;
                    u16* dst = ((sg - 1) & 1) ? P2 : P1;
                    dst[((size_t)(s * 32 + b) * 200 + o * 10 + l) * 512 + v] = f2bf(val);
                }
            }
        }
}

// ---------------- shared GEMM skeleton (v64 x col112 tile, 4 waves) ----------------
// wave wid owns v-frag wid (16 rows), all 7 col-frags.
// EPI = 0: T RMW (T := T + acc, bf16);  EPI = 1: f32 store to Ypart.
template <int EPI>
__device__ __forceinline__ void gemm_body(
    const float* __restrict__ A0, const float* __restrict__ A1, const float* __restrict__ A2,
    const u16* __restrict__ Xsrc, u16* __restrict__ Tdst, float* __restrict__ Ydst)
{
    __shared__ u16 sA[64 * 40];            // [64 v][32+8 pad]
    __shared__ u16 sX[112 * 40];           // [112 col][32+8 pad]

    // XCD-aware swizzle: 1536 blocks -> each XCD gets 192 contiguous eids (12 z's)
    const int bid = blockIdx.x + 8 * (blockIdx.y + 2 * blockIdx.z);
    const int eid = (bid & 7) * 192 + (bid >> 3);
    const int vblk = (eid & 7) * 64;
    const int colbase = ((eid >> 3) & 1) * 112;
    const int z = eid >> 4, s = z >> 5, b = z & 31;

    const float* Af = (s == 0 ? A0 : (s == 1 ? A1 : A2)) + (size_t)b * 512 * 512;
    const u16* Xb = Xsrc + (size_t)z * 200 * 512;

    const int t = threadIdx.x;
    const int lane = t & 63, wid = t >> 6;
    const int lrow = lane & 15, lk = (lane >> 4) * 8;

    // staging indices
    const int arow = t >> 2, ap2 = t & 3;          // A: 64 rows x 4 chunks of 8 f32
    const int xrow0 = t >> 2, xp = t & 3;          // X: ids t (<448) and t+256

    float4 ar0, ar1;
    u16x8 xr0, xr1;
    auto load_regs = [&](int kt) {
        const int w0 = kt * 32;
        const float* ap = Af + (size_t)(vblk + arow) * 512 + w0 + ap2 * 8;
        ar0 = *(const float4*)ap;
        ar1 = *(const float4*)(ap + 4);
        {
            int cg = colbase + xrow0;
            u16x8 zv = {};
            xr0 = (cg < 200) ? *(const u16x8*)(Xb + (size_t)cg * 512 + w0 + xp * 8) : zv;
        }
        if (t < 192) {
            int row = (t + 256) >> 2, p = (t + 256) & 3;
            int cg = colbase + row;
            u16x8 zv = {};
            xr1 = (cg < 200) ? *(const u16x8*)(Xb + (size_t)cg * 512 + w0 + p * 8) : zv;
        }
    };
    auto store_lds = [&]() {
        u16x8 pk = { f2bf(ar0.x), f2bf(ar0.y), f2bf(ar0.z), f2bf(ar0.w),
                     f2bf(ar1.x), f2bf(ar1.y), f2bf(ar1.z), f2bf(ar1.w) };
        *(u16x8*)(&sA[arow * 40 + ap2 * 8]) = pk;
        *(u16x8*)(&sX[xrow0 * 40 + xp * 8]) = xr0;
        if (t < 192) {
            int row = (t + 256) >> 2, p = (t + 256) & 3;
            *(u16x8*)(&sX[row * 40 + p * 8]) = xr1;
        }
    };

    f32x4 acc[7] = {};
    load_regs(0);
    for (int kt = 0; kt < 16; ++kt) {
        store_lds();
        __syncthreads();
        if (kt < 15) load_regs(kt + 1);
        bf16x8 af = *(const bf16x8*)(&sA[(wid * 16 + lrow) * 40 + lk]);
        #pragma unroll
        for (int cf = 0; cf < 7; ++cf) {
            bf16x8 xf = *(const bf16x8*)(&sX[(cf * 16 + lrow) * 40 + lk]);
            acc[cf] = __builtin_amdgcn_mfma_f32_16x16x32_bf16(xf, af, acc[cf], 0, 0, 0);
        }
        __syncthreads();
    }

    const int v = vblk + wid * 16 + (lane & 15);
    const int r4 = (lane >> 4) * 4;
    if (EPI == 0) {
        u16* Tz = Tdst + (size_t)z * 200 * 512;
        #pragma unroll
        for (int cf = 0; cf < 7; ++cf)
            #pragma unroll
            for (int i = 0; i < 4; ++i) {
                int col = colbase + cf * 16 + r4 + i;
                if (col < 200) {
                    size_t idx = (size_t)col * 512 + v;
                    Tz[idx] = f2bf(acc[cf][i] + bf2f(Tz[idx]));
                }
            }
    } else {
        float* Yz = Ydst + (size_t)z * 200 * 512;
        #pragma unroll
        for (int cf = 0; cf < 7; ++cf)
            #pragma unroll
            for (int i = 0; i < 4; ++i) {
                int col = colbase + cf * 16 + r4 + i;
                if (col < 200)
                    Yz[(size_t)col * 512 + v] = acc[cf][i];
            }
    }
}

__global__ __launch_bounds__(256) void gemm_t(
    const float* __restrict__ A0, const float* __restrict__ A1, const float* __restrict__ A2,
    const u16* __restrict__ P2, u16* __restrict__ T)
{
    gemm_body<0>(A0, A1, A2, P2, T, nullptr);
}

__global__ __launch_bounds__(256) void gemm_yp(
    const float* __restrict__ A0, const float* __restrict__ A1, const float* __restrict__ A2,
    const u16* __restrict__ T, float* __restrict__ Ypart)
{
    gemm_body<1>(A0, A1, A2, T, nullptr, Ypart);
}

// ---------------- K4: y = proj0 + bias + sum_s Ypart[s] ----------------
__global__ __launch_bounds__(256) void reduce_y(
    const float* __restrict__ Ypart, const float* __restrict__ proj0,
    const float* __restrict__ bias, float* __restrict__ y)
{
    int i = blockIdx.x * 256 + threadIdx.x;   // over 32*20*512
    if (i >= 32 * 20 * 512) return;
    int v = i & 511;
    int r = i >> 9;
    int o = r % 20, b = r / 20;
    float bb = bias[o];
    float* yp = y + ((size_t)r * 512 + v) * 10;
    #pragma unroll
    for (int l = 0; l < 10; ++l) {
        float sum = proj0[((size_t)r * 10 + l) * 512 + v] + bb;
        #pragma unroll
        for (int s = 0; s < 3; ++s)
            sum += Ypart[((size_t)(s * 32 + b) * 200 + o * 10 + l) * 512 + v];
        yp[l] = sum;
    }
}

extern "C" void kernel_launch(void* const* d_in, const int* in_sizes, int n_in,
                              void* d_out, int out_size, void* d_ws, size_t ws_size,
                              hipStream_t stream) {
    const float* x    = (const float*)d_in[0];
    const float* A0   = (const float*)d_in[1];
    const float* A1   = (const float*)d_in[2];
    const float* A2   = (const float*)d_in[3];
    const float* W    = (const float*)d_in[4];
    const float* bias = (const float*)d_in[5];
    float* y = (float*)d_out;

    // ws: P1/T [96][200][512] bf16 | P2 same | proj0 [32][20][10][512] f32 | Ypart [96][200][512] f32
    const size_t PSZ = (size_t)96 * 200 * 512;        // 9,830,400 elems
    u16* P1 = (u16*)d_ws;                             // 19.66 MB (becomes T in-place)
    u16* P2 = P1 + PSZ;                               // 19.66 MB
    float* proj0 = (float*)(P2 + PSZ);                // 13.11 MB
    float* Ypart = proj0 + (size_t)32 * 20 * 10 * 512;// 39.32 MB   (total 91.8 MB)

    proj_x<<<dim3(8, 10, 32), 256, 0, stream>>>(x, W, P1, P2, proj0);
    gemm_t<<<dim3(8, 2, 96), 256, 0, stream>>>(A0, A1, A2, P2, P1);      // T := P1 + A@P2
    gemm_yp<<<dim3(8, 2, 96), 256, 0, stream>>>(A0, A1, A2, P1, Ypart);  // Ypart = A@T
    reduce_y<<<dim3(1280), 256, 0, stream>>>(Ypart, proj0, bias, y);
}

// Round 5
// 107.546 us; speedup vs baseline: 4.9245x; 1.1248x over previous
//
#include <hip/hip_runtime.h>
#include <hip/hip_bf16.h>

// ddstgcn via conv/diffusion commutation:
//   y = proj0(x) + bias + sum_s A_s @ ( p1_s(x) + A_s @ p2_s(x) )
// K1 proj_x : 7 channel projections of x (one MFMA GEMM) -> P1, P2 (bf16), proj0 (f32)
// K2 gemm_t : T := P1 + A_s @ P2, in-place over P1.  per (s,b): M=512(v) N=200 K=512
// K3 gemm_yp: Ypart[s] = A_s @ T_s  (f32 partials, direct coalesced stores)
// K4 reduce : y = proj0 + bias + sum_s Ypart[s]
//
// Round-4: GEMM K-loop rebuilt on the T3 "minimum 2-phase" schedule:
//   global_load_lds(16B) DMA staging -> LDS double-buffer, ONE barrier per K-step.
//   A staged as f32 with XOR chunk-swizzle (pre-swizzled GLOBAL source + swizzled
//   ds_read, rule #21); X (bf16) natural 64B rows are already bank-uniform.
//   Tile 128v x 112col, 4 waves (1 wave = 32v x 112col = 2x7 frags), 46KB LDS,
//   grid 768 = 3 blocks/CU exact.

typedef unsigned short u16;
typedef u16 u16x4 __attribute__((ext_vector_type(4)));
typedef u16 u16x8 __attribute__((ext_vector_type(8)));
typedef __bf16 bf16x8 __attribute__((ext_vector_type(8)));
typedef float f32x4 __attribute__((ext_vector_type(4)));

#define GLD_LDS16(g, l)  __builtin_amdgcn_global_load_lds( \
    (const __attribute__((address_space(1))) void*)(g),    \
    (__attribute__((address_space(3))) void*)(l), 16, 0, 0)

__device__ __forceinline__ u16 f2bf(float f) {
    unsigned int u = __float_as_uint(f);
    u += 0x7fffu + ((u >> 16) & 1u);   // RNE
    return (u16)(u >> 16);
}
__device__ __forceinline__ float bf2f(u16 h) {
    return __uint_as_float(((unsigned int)h) << 16);
}

// ---------------- K1: fused 7-way projection of x ----------------
__global__ __launch_bounds__(256) void proj_x(
    const float* __restrict__ x, const float* __restrict__ W,
    u16* __restrict__ P1, u16* __restrict__ P2, float* __restrict__ proj0)
{
    __shared__ u16 sA[144 * 104];
    __shared__ u16 sB[64 * 104];
    const int t = threadIdx.x;
    const int v0 = blockIdx.x * 64, l = blockIdx.y, b = blockIdx.z;

    for (int id = t; id < 144 * 13; id += 256) {
        int m = id / 13, kc = id % 13, k0 = kc * 8;
        u16x8 val = {};
        if (m < 140 && k0 < 80) {
            int o = m % 20, sg = m / 20;
            const float* wp = W + o * 560 + sg * 80 + k0;
            float4 w0 = *(const float4*)wp;
            float4 w1 = *(const float4*)(wp + 4);
            val[0] = f2bf(w0.x); val[1] = f2bf(w0.y); val[2] = f2bf(w0.z); val[3] = f2bf(w0.w);
            val[4] = f2bf(w1.x); val[5] = f2bf(w1.y); val[6] = f2bf(w1.z); val[7] = f2bf(w1.w);
        }
        *(u16x8*)(&sA[m * 104 + k0]) = val;
    }
    for (int id = t; id < 5120; id += 256) {
        int v = id & 63, k = id >> 6;
        int c = k >> 1, tap = k & 1;
        float xv = x[((size_t)(b * 40 + c) * 512 + v0 + v) * 12 + l + 2 * tap];
        sB[v * 104 + k] = f2bf(xv);
    }
    for (int id = t; id < 64 * 3; id += 256) {
        int v = id / 3, j = id % 3;
        u16x8 z = {};
        *(u16x8*)(&sB[v * 104 + 80 + j * 8]) = z;
    }
    __syncthreads();

    const int lane = t & 63, wid = t >> 6;
    const int lrow = lane & 15, lk = (lane >> 4) * 8;
    f32x4 acc[9] = {};
    #pragma unroll
    for (int ks = 0; ks < 3; ++ks) {
        bf16x8 xf = *(const bf16x8*)(&sB[(wid * 16 + lrow) * 104 + ks * 32 + lk]);
        #pragma unroll
        for (int mf = 0; mf < 9; ++mf) {
            bf16x8 af = *(const bf16x8*)(&sA[(mf * 16 + lrow) * 104 + ks * 32 + lk]);
            acc[mf] = __builtin_amdgcn_mfma_f32_16x16x32_bf16(af, xf, acc[mf], 0, 0, 0);
        }
    }

    const int v = v0 + wid * 16 + lrow;
    const int r4 = (lane >> 4) * 4;
    #pragma unroll
    for (int mf = 0; mf < 9; ++mf)
        #pragma unroll
        for (int i = 0; i < 4; ++i) {
            int m = mf * 16 + r4 + i;
            if (m < 140) {
                int o = m % 20, sg = m / 20;
                float val = acc[mf][i];
                if (sg == 0) {
                    proj0[((size_t)(b * 20 + o) * 10 + l) * 512 + v] = val;
                } else {
                    int s = (sg - 1) >> 1;
                    u16* dst = ((sg - 1) & 1) ? P2 : P1;
                    dst[((size_t)(s * 32 + b) * 200 + o * 10 + l) * 512 + v] = f2bf(val);
                }
            }
        }
}

// ---------------- shared GEMM body: 2-phase DMA double-buffer ----------------
// tile 128v x 112col, BK=32, 16 K-steps, 4 waves (wave = 32v x 112col).
// EPI = 0: T := T + acc (bf16 RMW);  EPI = 1: f32 store to Ypart.
template <int EPI>
__device__ __forceinline__ void gemm_body(
    const float* __restrict__ A0, const float* __restrict__ A1, const float* __restrict__ A2,
    const u16* __restrict__ Xsrc, u16* __restrict__ Tdst, float* __restrict__ Ydst)
{
    __shared__ float sAf[2][128 * 32];   // A f32, rows of 128B, chunk-XOR swizzled (32KB)
    __shared__ u16   sXs[2][112 * 32];   // X bf16, rows of 64B, linear (14KB)

    // XCD swizzle: 768 blocks -> XCD gets 96 consecutive eids = 12 whole z's
    const int bid = blockIdx.x;
    const int eid = (bid & 7) * 96 + (bid >> 3);
    const int z = eid >> 3, rem = eid & 7;
    const int vblk = (rem >> 1) * 128;
    const int colbase = (rem & 1) * 112;
    const int s = z >> 5, b = z & 31;

    const float* Af = (s == 0 ? A0 : (s == 1 ? A1 : A2)) + (size_t)b * 512 * 512;
    const u16* Xb = Xsrc + (size_t)z * 200 * 512;

    const int t = threadIdx.x;
    const int lane = t & 63, wid = t >> 6;
    const int lr = lane & 15;
    const int kc0 = (lane >> 4) * 2;           // A chunk pair base (16B chunks)

    // --- DMA stage of K-step kt into buffer buf ---
    auto stage = [&](int kt, int buf) {
        const int w0 = kt * 32;
        float* ab = &sAf[buf][0];
        u16*   xb = &sXs[buf][0];
        // A: 128 rows x 128B = 16 wave-ops of 1KB; this wave does 4.
        // LDS is linear (dest = base + lane*16); SOURCE address carries the
        // chunk-XOR so that LDS[row][p] = G[row][p ^ (row&7)].
        #pragma unroll
        for (int i = 0; i < 4; ++i) {
            int op  = wid * 4 + i;
            int row = op * 8 + (lane >> 3);
            int pc  = lane & 7;
            const float* src = Af + (size_t)(vblk + row) * 512 + w0 + ((pc ^ (row & 7)) << 2);
            GLD_LDS16(src, ab + op * 256);
        }
        // X: 112 rows x 64B = 7 wave-ops of 1KB (waves 0-2 do 2, wave 3 does 1)
        #pragma unroll
        for (int i = 0; i < 2; ++i) {
            int op = wid + i * 4;
            if (op < 7) {
                int row = op * 16 + (lane >> 2);
                int ch  = lane & 3;
                const u16* src = Xb + (size_t)(colbase + row) * 512 + w0 + ch * 8;
                GLD_LDS16(src, xb + op * 512);
            }
        }
    };

    f32x4 acc[7][2] = {};

    stage(0, 0);
    __syncthreads();                      // drain prologue DMA

    for (int kt = 0; kt < 16; ++kt) {
        const int cur = kt & 1;
        if (kt < 15) stage(kt + 1, cur ^ 1);   // in flight across this step's compute

        // A fragments: f32 swizzled read + cvt to bf16
        bf16x8 af[2];
        #pragma unroll
        for (int mf = 0; mf < 2; ++mf) {
            int r = wid * 32 + mf * 16 + lr;
            const float* rb = &sAf[cur][r * 32];
            f32x4 a0 = *(const f32x4*)(rb + ((kc0 ^ (r & 7)) << 2));
            f32x4 a1 = *(const f32x4*)(rb + (((kc0 + 1) ^ (r & 7)) << 2));
            union { u16x8 u; bf16x8 bv; } cv;
            cv.u = (u16x8){ f2bf(a0[0]), f2bf(a0[1]), f2bf(a0[2]), f2bf(a0[3]),
                            f2bf(a1[0]), f2bf(a1[1]), f2bf(a1[2]), f2bf(a1[3]) };
            af[mf] = cv.bv;
        }
        #pragma unroll
        for (int cf = 0; cf < 7; ++cf) {
            bf16x8 xf = *(const bf16x8*)(&sXs[cur][(cf * 16 + lr) * 32 + (lane >> 4) * 8]);
            #pragma unroll
            for (int mf = 0; mf < 2; ++mf)
                acc[cf][mf] = __builtin_amdgcn_mfma_f32_16x16x32_bf16(
                    xf, af[mf], acc[cf][mf], 0, 0, 0);
        }
        __syncthreads();                  // one barrier per K-step (drains DMA too)
    }

    const int r4 = (lane >> 4) * 4;
    if (EPI == 0) {
        u16* Tz = Tdst + (size_t)z * 200 * 512;
        #pragma unroll
        for (int cf = 0; cf < 7; ++cf)
            #pragma unroll
            for (int mf = 0; mf < 2; ++mf)
                #pragma unroll
                for (int i = 0; i < 4; ++i) {
                    int col = colbase + cf * 16 + r4 + i;
                    if (col < 200) {
                        size_t idx = (size_t)col * 512 + vblk + wid * 32 + mf * 16 + lr;
                        Tz[idx] = f2bf(acc[cf][mf][i] + bf2f(Tz[idx]));
                    }
                }
    } else {
        float* Yz = Ydst + (size_t)z * 200 * 512;
        #pragma unroll
        for (int cf = 0; cf < 7; ++cf)
            #pragma unroll
            for (int mf = 0; mf < 2; ++mf)
                #pragma unroll
                for (int i = 0; i < 4; ++i) {
                    int col = colbase + cf * 16 + r4 + i;
                    if (col < 200)
                        Yz[(size_t)col * 512 + vblk + wid * 32 + mf * 16 + lr] = acc[cf][mf][i];
                }
    }
}

__global__ __launch_bounds__(256) void gemm_t(
    const float* __restrict__ A0, const float* __restrict__ A1, const float* __restrict__ A2,
    const u16* __restrict__ P2, u16* __restrict__ T)
{
    gemm_body<0>(A0, A1, A2, P2, T, nullptr);
}

__global__ __launch_bounds__(256) void gemm_yp(
    const float* __restrict__ A0, const float* __restrict__ A1, const float* __restrict__ A2,
    const u16* __restrict__ T, float* __restrict__ Ypart)
{
    gemm_body<1>(A0, A1, A2, T, nullptr, Ypart);
}

// ---------------- K4: y = proj0 + bias + sum_s Ypart[s] ----------------
__global__ __launch_bounds__(256) void reduce_y(
    const float* __restrict__ Ypart, const float* __restrict__ proj0,
    const float* __restrict__ bias, float* __restrict__ y)
{
    int i = blockIdx.x * 256 + threadIdx.x;   // over 32*20*512
    if (i >= 32 * 20 * 512) return;
    int v = i & 511;
    int r = i >> 9;
    int o = r % 20, b = r / 20;
    float bb = bias[o];
    float* yp = y + ((size_t)r * 512 + v) * 10;
    #pragma unroll
    for (int l = 0; l < 10; ++l) {
        float sum = proj0[((size_t)r * 10 + l) * 512 + v] + bb;
        #pragma unroll
        for (int s = 0; s < 3; ++s)
            sum += Ypart[((size_t)(s * 32 + b) * 200 + o * 10 + l) * 512 + v];
        yp[l] = sum;
    }
}

extern "C" void kernel_launch(void* const* d_in, const int* in_sizes, int n_in,
                              void* d_out, int out_size, void* d_ws, size_t ws_size,
                              hipStream_t stream) {
    const float* x    = (const float*)d_in[0];
    const float* A0   = (const float*)d_in[1];
    const float* A1   = (const float*)d_in[2];
    const float* A2   = (const float*)d_in[3];
    const float* W    = (const float*)d_in[4];
    const float* bias = (const float*)d_in[5];
    float* y = (float*)d_out;

    // ws: P1/T [96][200][512] bf16 | P2 same | proj0 [32][20][10][512] f32 | Ypart [96][200][512] f32
    const size_t PSZ = (size_t)96 * 200 * 512;        // 9,830,400 elems
    u16* P1 = (u16*)d_ws;                             // 19.66 MB (becomes T in-place)
    u16* P2 = P1 + PSZ;                               // 19.66 MB
    float* proj0 = (float*)(P2 + PSZ);                // 13.11 MB
    float* Ypart = proj0 + (size_t)32 * 20 * 10 * 512;// 39.32 MB   (total 91.8 MB)

    proj_x<<<dim3(8, 10, 32), 256, 0, stream>>>(x, W, P1, P2, proj0);
    gemm_t<<<dim3(768), 256, 0, stream>>>(A0, A1, A2, P2, P1);       // T := P1 + A@P2
    gemm_yp<<<dim3(768), 256, 0, stream>>>(A0, A1, A2, P1, Ypart);   // Ypart = A@T
    reduce_y<<<dim3(1280), 256, 0, stream>>>(Ypart, proj0, bias, y);
}

// Round 6
// 105.167 us; speedup vs baseline: 5.0359x; 1.0226x over previous
//
#include <hip/hip_runtime.h>
#include <hip/hip_bf16.h>

// ddstgcn via conv/diffusion commutation:
//   y = proj0(x) + bias + sum_s A_s @ ( p1_s(x) + A_s @ p2_s(x) )
// K0 xpose  : x[b,c,v,l] f32 -> xq[b][l][v][48] bf16 (c contiguous, pad 40..47 = 0)
// K1 proj_x : 7 channel projections as MFMA GEMM, K-order k=tap*40+c, B-tiles DMA'd
//             from xq (linear dest), all 10 l's per block, W staged once.
// K2 gemm_t : T := P1 + A_s @ P2, in-place over P1 (DMA 2-phase, 128x112 tile)
// K3 gemm_yp: Ypart[s] = A_s @ T_s
// K4 reduce : y = proj0 + bias + sum_s Ypart[s]

typedef unsigned short u16;
typedef u16 u16x4 __attribute__((ext_vector_type(4)));
typedef u16 u16x8 __attribute__((ext_vector_type(8)));
typedef __bf16 bf16x8 __attribute__((ext_vector_type(8)));
typedef float f32x4 __attribute__((ext_vector_type(4)));

#define GLD_LDS16(g, l)  __builtin_amdgcn_global_load_lds( \
    (const __attribute__((address_space(1))) void*)(g),    \
    (__attribute__((address_space(3))) void*)(l), 16, 0, 0)

__device__ __forceinline__ u16 f2bf(float f) {
    unsigned int u = __float_as_uint(f);
    u += 0x7fffu + ((u >> 16) & 1u);   // RNE
    return (u16)(u >> 16);
}
__device__ __forceinline__ float bf2f(u16 h) {
    return __uint_as_float(((unsigned int)h) << 16);
}

// ---------------- K0: x[b,c,v,l] f32 -> xq[b][l][v][48] bf16 ----------------
// thread = (v lane, c-group of 12). Reads: lane-consecutive v, 48B each -> full-line
// coalescing. Writes: u16x4 x3 per l, L2-merged across c-groups.
__global__ __launch_bounds__(256) void xpose(const float* __restrict__ x,
                                             u16* __restrict__ xq)
{
    const int t = threadIdx.x, vloc = t & 63, cg = t >> 6;
    const int v = blockIdx.x * 64 + vloc, b = blockIdx.y;

    u16 vals[12][12];                  // [l][ci], all-static indexing
    #pragma unroll
    for (int ci = 0; ci < 12; ++ci) {
        int c = cg * 12 + ci;
        if (c < 40) {
            const float* xp = x + ((size_t)(b * 40 + c) * 512 + v) * 12;
            float4 f0 = *(const float4*)xp;
            float4 f1 = *(const float4*)(xp + 4);
            float4 f2 = *(const float4*)(xp + 8);
            vals[0][ci] = f2bf(f0.x);  vals[1][ci] = f2bf(f0.y);
            vals[2][ci] = f2bf(f0.z);  vals[3][ci] = f2bf(f0.w);
            vals[4][ci] = f2bf(f1.x);  vals[5][ci] = f2bf(f1.y);
            vals[6][ci] = f2bf(f1.z);  vals[7][ci] = f2bf(f1.w);
            vals[8][ci] = f2bf(f2.x);  vals[9][ci] = f2bf(f2.y);
            vals[10][ci] = f2bf(f2.z); vals[11][ci] = f2bf(f2.w);
        } else {
            #pragma unroll
            for (int l = 0; l < 12; ++l) vals[l][ci] = 0;
        }
    }
    #pragma unroll
    for (int l = 0; l < 12; ++l) {
        u16* dst = xq + ((size_t)(b * 12 + l) * 512 + v) * 48 + cg * 12;
        u16x4 a = { vals[l][0], vals[l][1], vals[l][2], vals[l][3] };
        u16x4 c4 = { vals[l][4], vals[l][5], vals[l][6], vals[l][7] };
        u16x4 d = { vals[l][8], vals[l][9], vals[l][10], vals[l][11] };
        *(u16x4*)(dst) = a;
        *(u16x4*)(dst + 4) = c4;
        *(u16x4*)(dst + 8) = d;
    }
}

// ---------------- K1: fused 7-way projection of x ----------------
// block = (b, vtile 64); all 10 l's, all 140 m = sg*20+o.
// A[m][k=tap*40+c] = W[o,sg*40+c,tap] staged once; B-tile [2tap][64v][48c] bf16
// DMA'd per l (double-buffered). MFMA k-slices never cross the tap/pad boundaries
// (40, 80 are multiples of 8), so every fragment read is one contiguous b128.
__global__ __launch_bounds__(256) void proj_x(
    const u16* __restrict__ xq, const float* __restrict__ W,
    u16* __restrict__ P1, u16* __restrict__ P2, float* __restrict__ proj0)
{
    __shared__ u16 sA[144 * 104];        // 29.95 KB, k-pad 80..103 zero
    __shared__ u16 sB[2][2 * 64 * 48];   // 24.6 KB: [buf][tap][v][48]

    const int t = threadIdx.x, lane = t & 63, wid = t >> 6;
    const int b = blockIdx.y, v0 = blockIdx.x * 64;

    // stage W -> sA with k=tap*40+c ordering (16 consecutive f32 = 8 c's x 2 taps)
    for (int id = t; id < 144 * 5; id += 256) {
        int m = id / 5, c0 = (id % 5) * 8;
        u16x8 e = {}, o8 = {};
        if (m < 140) {
            int o = m % 20, sg = m / 20;
            const float* wp = W + o * 560 + sg * 80 + c0 * 2;
            float4 a = *(const float4*)wp;
            float4 bb = *(const float4*)(wp + 4);
            float4 c = *(const float4*)(wp + 8);
            float4 d = *(const float4*)(wp + 12);
            e[0] = f2bf(a.x);  o8[0] = f2bf(a.y);  e[1] = f2bf(a.z);  o8[1] = f2bf(a.w);
            e[2] = f2bf(bb.x); o8[2] = f2bf(bb.y); e[3] = f2bf(bb.z); o8[3] = f2bf(bb.w);
            e[4] = f2bf(c.x);  o8[4] = f2bf(c.y);  e[5] = f2bf(c.z);  o8[5] = f2bf(c.w);
            e[6] = f2bf(d.x);  o8[6] = f2bf(d.y);  e[7] = f2bf(d.z);  o8[7] = f2bf(d.w);
        }
        *(u16x8*)(&sA[m * 104 + c0]) = e;        // tap0: k = c
        *(u16x8*)(&sA[m * 104 + 40 + c0]) = o8;  // tap1: k = 40 + c
    }
    for (int id = t; id < 144 * 3; id += 256) {  // zero k 80..103
        int m = id / 3, k0 = 80 + (id % 3) * 8;
        u16x8 z = {};
        *(u16x8*)(&sA[m * 104 + k0]) = z;
    }

    // B-tile DMA: 12 ops of 1KB (6 per tap plane); source rows [v][48] contiguous.
    auto stage = [&](int l, int buf) {
        u16* dst = &sB[buf][0];
        #pragma unroll
        for (int i = 0; i < 3; ++i) {
            int op = wid * 3 + i;            // 0..11
            int tap = op / 6, rem = op % 6;
            const u16* src = xq + ((size_t)(b * 12 + l + 2 * tap) * 512 + v0) * 48
                             + rem * 512 + lane * 8;
            GLD_LDS16(src, dst + tap * 3072 + rem * 512);
        }
    };

    stage(0, 0);
    __syncthreads();                     // drains sA ds_writes + prologue DMA

    // hoist all 27 A fragments (k contiguous in sA by construction)
    const int lr = lane & 15, q = lane >> 4;
    bf16x8 af[9][3];
    #pragma unroll
    for (int mf = 0; mf < 9; ++mf)
        #pragma unroll
        for (int s = 0; s < 3; ++s)
            af[mf][s] = *(const bf16x8*)(&sA[(mf * 16 + lr) * 104 + s * 32 + q * 8]);

    // B-frag LDS offsets per k-slice (k0 = s*32 + q*8)
    const int voff = (wid * 16 + lr) * 48;
    int boff[3];
    #pragma unroll
    for (int s = 0; s < 3; ++s) {
        int k = s * 32 + q * 8;
        int tap, c;
        if (k < 40)      { tap = 0; c = k; }
        else if (k < 80) { tap = 1; c = k - 40; }
        else             { tap = 1; c = 40; }   // zero pad region
        boff[s] = tap * 3072 + voff + c;
    }

    const int v = v0 + wid * 16 + lr;
    for (int l = 0; l < 10; ++l) {
        const int cur = l & 1;
        if (l < 9) stage(l + 1, cur ^ 1);

        const u16* bb = &sB[cur][0];
        bf16x8 xf[3];
        #pragma unroll
        for (int s = 0; s < 3; ++s) xf[s] = *(const bf16x8*)(bb + boff[s]);

        f32x4 acc[9] = {};
        #pragma unroll
        for (int s = 0; s < 3; ++s)
            #pragma unroll
            for (int mf = 0; mf < 9; ++mf)
                acc[mf] = __builtin_amdgcn_mfma_f32_16x16x32_bf16(
                    af[mf][s], xf[s], acc[mf], 0, 0, 0);

        #pragma unroll
        for (int mf = 0; mf < 9; ++mf)
            #pragma unroll
            for (int i = 0; i < 4; ++i) {
                int m = mf * 16 + q * 4 + i;
                if (m < 140) {
                    int o = m % 20, sg = m / 20;
                    float val = acc[mf][i];
                    if (sg == 0) {
                        proj0[((size_t)(b * 20 + o) * 10 + l) * 512 + v] = val;
                    } else {
                        int s2 = (sg - 1) >> 1;
                        u16* dst = ((sg - 1) & 1) ? P2 : P1;
                        dst[((size_t)(s2 * 32 + b) * 200 + o * 10 + l) * 512 + v] = f2bf(val);
                    }
                }
            }
        __syncthreads();                 // next buffer's DMA complete; cur reusable
    }
}

// ---------------- shared GEMM body: 2-phase DMA double-buffer ----------------
// tile 128v x 112col, BK=32, 16 K-steps, 4 waves (wave = 32v x 112col).
// EPI = 0: T := T + acc (bf16 RMW);  EPI = 1: f32 store to Ypart.
template <int EPI>
__device__ __forceinline__ void gemm_body(
    const float* __restrict__ A0, const float* __restrict__ A1, const float* __restrict__ A2,
    const u16* __restrict__ Xsrc, u16* __restrict__ Tdst, float* __restrict__ Ydst)
{
    __shared__ float sAf[2][128 * 32];   // A f32, rows of 128B, chunk-XOR swizzled (32KB)
    __shared__ u16   sXs[2][112 * 32];   // X bf16, rows of 64B, linear (14KB)

    // XCD swizzle: 768 blocks -> XCD gets 96 consecutive eids = 12 whole z's
    const int bid = blockIdx.x;
    const int eid = (bid & 7) * 96 + (bid >> 3);
    const int z = eid >> 3, rem = eid & 7;
    const int vblk = (rem >> 1) * 128;
    const int colbase = (rem & 1) * 112;
    const int s = z >> 5, b = z & 31;

    const float* Af = (s == 0 ? A0 : (s == 1 ? A1 : A2)) + (size_t)b * 512 * 512;
    const u16* Xb = Xsrc + (size_t)z * 200 * 512;

    const int t = threadIdx.x;
    const int lane = t & 63, wid = t >> 6;
    const int lr = lane & 15;
    const int kc0 = (lane >> 4) * 2;           // A chunk pair base (16B chunks)

    auto stage = [&](int kt, int buf) {
        const int w0 = kt * 32;
        float* ab = &sAf[buf][0];
        u16*   xb = &sXs[buf][0];
        #pragma unroll
        for (int i = 0; i < 4; ++i) {
            int op  = wid * 4 + i;
            int row = op * 8 + (lane >> 3);
            int pc  = lane & 7;
            const float* src = Af + (size_t)(vblk + row) * 512 + w0 + ((pc ^ (row & 7)) << 2);
            GLD_LDS16(src, ab + op * 256);
        }
        #pragma unroll
        for (int i = 0; i < 2; ++i) {
            int op = wid + i * 4;
            if (op < 7) {
                int row = op * 16 + (lane >> 2);
                int ch  = lane & 3;
                const u16* src = Xb + (size_t)(colbase + row) * 512 + w0 + ch * 8;
                GLD_LDS16(src, xb + op * 512);
            }
        }
    };

    f32x4 acc[7][2] = {};

    stage(0, 0);
    __syncthreads();

    for (int kt = 0; kt < 16; ++kt) {
        const int cur = kt & 1;
        if (kt < 15) stage(kt + 1, cur ^ 1);

        bf16x8 af[2];
        #pragma unroll
        for (int mf = 0; mf < 2; ++mf) {
            int r = wid * 32 + mf * 16 + lr;
            const float* rb = &sAf[cur][r * 32];
            f32x4 a0 = *(const f32x4*)(rb + ((kc0 ^ (r & 7)) << 2));
            f32x4 a1 = *(const f32x4*)(rb + (((kc0 + 1) ^ (r & 7)) << 2));
            union { u16x8 u; bf16x8 bv; } cv;
            cv.u = (u16x8){ f2bf(a0[0]), f2bf(a0[1]), f2bf(a0[2]), f2bf(a0[3]),
                            f2bf(a1[0]), f2bf(a1[1]), f2bf(a1[2]), f2bf(a1[3]) };
            af[mf] = cv.bv;
        }
        #pragma unroll
        for (int cf = 0; cf < 7; ++cf) {
            bf16x8 xf = *(const bf16x8*)(&sXs[cur][(cf * 16 + lr) * 32 + (lane >> 4) * 8]);
            #pragma unroll
            for (int mf = 0; mf < 2; ++mf)
                acc[cf][mf] = __builtin_amdgcn_mfma_f32_16x16x32_bf16(
                    xf, af[mf], acc[cf][mf], 0, 0, 0);
        }
        __syncthreads();
    }

    const int r4 = (lane >> 4) * 4;
    if (EPI == 0) {
        u16* Tz = Tdst + (size_t)z * 200 * 512;
        #pragma unroll
        for (int cf = 0; cf < 7; ++cf)
            #pragma unroll
            for (int mf = 0; mf < 2; ++mf)
                #pragma unroll
                for (int i = 0; i < 4; ++i) {
                    int col = colbase + cf * 16 + r4 + i;
                    if (col < 200) {
                        size_t idx = (size_t)col * 512 + vblk + wid * 32 + mf * 16 + lr;
                        Tz[idx] = f2bf(acc[cf][mf][i] + bf2f(Tz[idx]));
                    }
                }
    } else {
        float* Yz = Ydst + (size_t)z * 200 * 512;
        #pragma unroll
        for (int cf = 0; cf < 7; ++cf)
            #pragma unroll
            for (int mf = 0; mf < 2; ++mf)
                #pragma unroll
                for (int i = 0; i < 4; ++i) {
                    int col = colbase + cf * 16 + r4 + i;
                    if (col < 200)
                        Yz[(size_t)col * 512 + vblk + wid * 32 + mf * 16 + lr] = acc[cf][mf][i];
                }
    }
}

__global__ __launch_bounds__(256) void gemm_t(
    const float* __restrict__ A0, const float* __restrict__ A1, const float* __restrict__ A2,
    const u16* __restrict__ P2, u16* __restrict__ T)
{
    gemm_body<0>(A0, A1, A2, P2, T, nullptr);
}

__global__ __launch_bounds__(256) void gemm_yp(
    const float* __restrict__ A0, const float* __restrict__ A1, const float* __restrict__ A2,
    const u16* __restrict__ T, float* __restrict__ Ypart)
{
    gemm_body<1>(A0, A1, A2, T, nullptr, Ypart);
}

// ---------------- K4: y = proj0 + bias + sum_s Ypart[s] ----------------
__global__ __launch_bounds__(256) void reduce_y(
    const float* __restrict__ Ypart, const float* __restrict__ proj0,
    const float* __restrict__ bias, float* __restrict__ y)
{
    int i = blockIdx.x * 256 + threadIdx.x;   // over 32*20*512
    if (i >= 32 * 20 * 512) return;
    int v = i & 511;
    int r = i >> 9;
    int o = r % 20, b = r / 20;
    float bb = bias[o];
    float* yp = y + ((size_t)r * 512 + v) * 10;
    #pragma unroll
    for (int l = 0; l < 10; ++l) {
        float sum = proj0[((size_t)r * 10 + l) * 512 + v] + bb;
        #pragma unroll
        for (int s = 0; s < 3; ++s)
            sum += Ypart[((size_t)(s * 32 + b) * 200 + o * 10 + l) * 512 + v];
        yp[l] = sum;
    }
}

extern "C" void kernel_launch(void* const* d_in, const int* in_sizes, int n_in,
                              void* d_out, int out_size, void* d_ws, size_t ws_size,
                              hipStream_t stream) {
    const float* x    = (const float*)d_in[0];
    const float* A0   = (const float*)d_in[1];
    const float* A1   = (const float*)d_in[2];
    const float* A2   = (const float*)d_in[3];
    const float* W    = (const float*)d_in[4];
    const float* bias = (const float*)d_in[5];
    float* y = (float*)d_out;

    // ws: P1/T [96][200][512] bf16 | P2 same | proj0 f32 | Ypart [96][200][512] f32.
    // xq[32][12][512][48] bf16 (18.9MB) aliases Ypart (lifetimes disjoint). 91.8 MB total.
    const size_t PSZ = (size_t)96 * 200 * 512;
    u16* P1 = (u16*)d_ws;
    u16* P2 = P1 + PSZ;
    float* proj0 = (float*)(P2 + PSZ);
    float* Ypart = proj0 + (size_t)32 * 20 * 10 * 512;
    u16* xq = (u16*)Ypart;                            // alias: dead before gemm_yp

    xpose<<<dim3(8, 32), 256, 0, stream>>>(x, xq);
    proj_x<<<dim3(8, 32), 256, 0, stream>>>(xq, W, P1, P2, proj0);
    gemm_t<<<dim3(768), 256, 0, stream>>>(A0, A1, A2, P2, P1);       // T := P1 + A@P2
    gemm_yp<<<dim3(768), 256, 0, stream>>>(A0, A1, A2, P1, Ypart);   // Ypart = A@T
    reduce_y<<<dim3(1280), 256, 0, stream>>>(Ypart, proj0, bias, y);
}